// Round 1
// baseline (390.756 us; speedup 1.0000x reference)
//
#include <hip/hip_runtime.h>

#define NN 8192
#define DD 256

typedef __attribute__((ext_vector_type(8))) short short8;   // 8 bf16 (4 VGPR) MFMA frag
typedef __attribute__((ext_vector_type(4))) float f32x4;    // MFMA accumulator

__device__ __forceinline__ short f2bf(float x) {
    union { float f; unsigned u; } v; v.f = x;
    unsigned r = (v.u + 0x7FFFu + ((v.u >> 16) & 1u)) >> 16;  // RNE
    return (short)r;
}
__device__ __forceinline__ float bf2f(short b) {
    union { float f; unsigned u; } v; v.u = ((unsigned)(unsigned short)b) << 16;
    return v.f;
}

// Kernel 1: h = x@W (fp32 exact-ish); emit hT (bf16, [D][N] transposed),
// e_src[i] = h[i,:]. a[0:D], e_dst[i] = h[i,:] . a[D:2D]
__global__ __launch_bounds__(256) void gat_prep(
    const float* __restrict__ x, const float* __restrict__ W,
    const float* __restrict__ a,
    short* __restrict__ hT, float* __restrict__ e_src, float* __restrict__ e_dst)
{
    __shared__ float x_s[32][257];            // +1 pad: kill 8-way broadcast-group conflict
    const int t  = threadIdx.x;
    const int ib = blockIdx.x * 32;

    // stage x tile [32][256] coalesced (2048 float4 / 256 threads = 8 reps)
    for (int rep = 0; rep < 8; ++rep) {
        int fi = rep * 256 + t;               // float4 index; 64 float4 per row
        int r  = fi >> 6;
        int c4 = (fi & 63) * 4;
        float4 v = *(const float4*)(x + (size_t)(ib + r) * DD + c4);
        x_s[r][c4] = v.x; x_s[r][c4+1] = v.y; x_s[r][c4+2] = v.z; x_s[r][c4+3] = v.w;
    }
    __syncthreads();

    const int il = t >> 3;                    // local row 0..31
    const int d0 = (t & 7) * 32;              // 32 output cols per thread
    float acc[32];
    #pragma unroll
    for (int m = 0; m < 32; ++m) acc[m] = 0.f;

    for (int k = 0; k < DD; ++k) {
        float xv = x_s[il][k];
        const float4* wr = (const float4*)(W + (size_t)k * DD + d0);
        #pragma unroll
        for (int m = 0; m < 8; ++m) {
            float4 wv = wr[m];
            acc[4*m+0] += xv * wv.x;
            acc[4*m+1] += xv * wv.y;
            acc[4*m+2] += xv * wv.z;
            acc[4*m+3] += xv * wv.w;
        }
    }

    const int ig = ib + il;
    float p1 = 0.f, p2 = 0.f;
    #pragma unroll
    for (int m = 0; m < 32; ++m) {
        float hv = acc[m];
        p1 += hv * a[d0 + m];
        p2 += hv * a[DD + d0 + m];
        hT[(size_t)(d0 + m) * NN + ig] = f2bf(hv);   // transposed bf16 store
    }
    // reduce across the 8 consecutive lanes sharing a row
    p1 += __shfl_xor(p1, 1); p1 += __shfl_xor(p1, 2); p1 += __shfl_xor(p1, 4);
    p2 += __shfl_xor(p2, 1); p2 += __shfl_xor(p2, 2); p2 += __shfl_xor(p2, 4);
    if ((t & 7) == 0) { e_src[ig] = p1; e_dst[ig] = p2; }
}

// Kernel 2: fused masked softmax + attention@h.
// Block = 512 thr (8 waves), BM=32 rows x full D=256, K-step = 32 j's.
// Wave w: i-half = w&1 (16 rows), d-quarter = w>>1 (64 cols) -> 4 MFMAs/step.
__global__ __launch_bounds__(512) void gat_main(
    const int* __restrict__ adj, const short* __restrict__ hT,
    const float* __restrict__ e_src, const float* __restrict__ e_dst,
    float* __restrict__ out)
{
    __shared__ __align__(16) short B_s[2][256][40];   // hT panel, stride 40 (2-way = free)
    __shared__ __align__(16) short w_s[2][32][40];    // weight tile bf16
    __shared__ float denom_s[32];

    const int t    = threadIdx.x;
    const int lane = t & 63;
    const int wid  = t >> 6;
    const int ibl  = blockIdx.x * 32;

    // weight-tile builder mapping: 32 rows x 32 j / 512 thr = 2 j per thread
    const int irow = t >> 4;                  // 0..31
    const int jc2  = (t & 15) * 2;
    const float es = e_src[ibl + irow];
    const int* adj_row = adj + (size_t)(ibl + irow) * NN;
    // B staging mapping: thread -> d-row t>>1, 32B half (t&1)
    const short* hrow = hT + (size_t)(t >> 1) * NN + (t & 1) * 16;

    const int ihalf = wid & 1;
    const int dbase = (wid >> 1) * 64;
    const int arow  = lane & 15;              // frag row (A) / col (B,D)
    const int kg8   = (lane >> 4) * 8;        // frag k-chunk

    float dsum = 0.f;
    f32x4 acc0 = {0.f,0.f,0.f,0.f}, acc1 = acc0, acc2 = acc0, acc3 = acc0;

    // prologue loads (step 0)
    int2   ad = *(const int2*)(adj_row + jc2);
    float2 ed = *(const float2*)(e_dst + jc2);
    int4   h0 = *(const int4*)(hrow);
    int4   h1 = *(const int4*)(hrow + 8);

    for (int n = 0; n < NN / 32; ++n) {
        const int c = n & 1;
        int2 adc = ad; float2 edc = ed; int4 g0 = h0, g1 = h1;

        // prefetch next step's globals (hides HBM/L2 latency across the step)
        int jn = ((n + 1) & (NN / 32 - 1)) * 32;
        ad = *(const int2*)(adj_row + jn + jc2);
        ed = *(const float2*)(e_dst + jn + jc2);
        h0 = *(const int4*)(hrow + jn);
        h1 = *(const int4*)(hrow + jn + 8);

        // build weights: w = adj ? exp(leakyrelu(e_src+e_dst)) : 0
        float s0 = es + edc.x, s1 = es + edc.y;
        float l0 = s0 > 0.f ? s0 : 0.01f * s0;
        float l1 = s1 > 0.f ? s1 : 0.01f * s1;
        float w0 = adc.x > 0 ? __expf(l0) : 0.f;
        float w1 = adc.y > 0 ? __expf(l1) : 0.f;
        short b0 = f2bf(w0), b1 = f2bf(w1);
        dsum += bf2f(b0) + bf2f(b1);          // denom uses the SAME bf16-rounded weights
        *(unsigned*)&w_s[c][irow][jc2] =
            (unsigned)(unsigned short)b0 | ((unsigned)(unsigned short)b1 << 16);
        *(int4*)&B_s[c][t >> 1][(t & 1) * 16]     = g0;
        *(int4*)&B_s[c][t >> 1][(t & 1) * 16 + 8] = g1;
        __syncthreads();                       // single barrier/step (double-buffered)

        short8 af  = *(const short8*)&w_s[c][ihalf * 16 + arow][kg8];
        short8 bf0 = *(const short8*)&B_s[c][dbase +  0 + arow][kg8];
        short8 bf1 = *(const short8*)&B_s[c][dbase + 16 + arow][kg8];
        short8 bf2 = *(const short8*)&B_s[c][dbase + 32 + arow][kg8];
        short8 bf3 = *(const short8*)&B_s[c][dbase + 48 + arow][kg8];
        acc0 = __builtin_amdgcn_mfma_f32_16x16x32_bf16(af, bf0, acc0, 0, 0, 0);
        acc1 = __builtin_amdgcn_mfma_f32_16x16x32_bf16(af, bf1, acc1, 0, 0, 0);
        acc2 = __builtin_amdgcn_mfma_f32_16x16x32_bf16(af, bf2, acc2, 0, 0, 0);
        acc3 = __builtin_amdgcn_mfma_f32_16x16x32_bf16(af, bf3, acc3, 0, 0, 0);
    }

    // denom: 16 threads per row (consecutive lanes) -> shfl tree
    dsum += __shfl_xor(dsum, 1);
    dsum += __shfl_xor(dsum, 2);
    dsum += __shfl_xor(dsum, 4);
    dsum += __shfl_xor(dsum, 8);
    if ((t & 15) == 0) denom_s[irow] = dsum;
    __syncthreads();

    // epilogue: D-frag row=(lane>>4)*4+r, col=lane&15 (verified C/D layout)
    const int rbase = ihalf * 16 + (lane >> 4) * 4;
    #pragma unroll
    for (int r = 0; r < 4; ++r) {
        float inv = 1.f / denom_s[rbase + r];
        size_t o = (size_t)(ibl + rbase + r) * DD + dbase + arow;
        float v0 = acc0[r] * inv; v0 = v0 > 0.f ? v0 : expm1f(v0);
        float v1 = acc1[r] * inv; v1 = v1 > 0.f ? v1 : expm1f(v1);
        float v2 = acc2[r] * inv; v2 = v2 > 0.f ? v2 : expm1f(v2);
        float v3 = acc3[r] * inv; v3 = v3 > 0.f ? v3 : expm1f(v3);
        out[o] = v0; out[o + 16] = v1; out[o + 32] = v2; out[o + 48] = v3;
    }
}

extern "C" void kernel_launch(void* const* d_in, const int* in_sizes, int n_in,
                              void* d_out, int out_size, void* d_ws, size_t ws_size,
                              hipStream_t stream) {
    const float* x   = (const float*)d_in[0];
    const int*   adj = (const int*)d_in[1];
    const float* W   = (const float*)d_in[2];
    const float* a   = (const float*)d_in[3];
    float* out = (float*)d_out;

    // workspace: hT bf16 [256][8192] (4 MB) | e_src [8192] f32 | e_dst [8192] f32
    short* hT   = (short*)d_ws;
    float* esrc = (float*)((char*)d_ws + (size_t)DD * NN * 2);
    float* edst = esrc + NN;

    gat_prep<<<dim3(NN / 32), dim3(256), 0, stream>>>(x, W, a, hT, esrc, edst);
    gat_main<<<dim3(NN / 32), dim3(512), 0, stream>>>(adj, hT, esrc, edst, out);
}

// Round 2
// 209.930 us; speedup vs baseline: 1.8614x; 1.8614x over previous
//
#include <hip/hip_runtime.h>

#define NN 8192
#define DD 256

typedef __attribute__((ext_vector_type(8))) short short8;   // 8 bf16 (4 VGPR) MFMA frag
typedef __attribute__((ext_vector_type(4))) float f32x4;    // MFMA accumulator

__device__ __forceinline__ short f2bf(float x) {
    union { float f; unsigned u; } v; v.f = x;
    unsigned r = (v.u + 0x7FFFu + ((v.u >> 16) & 1u)) >> 16;  // RNE
    return (short)r;
}
__device__ __forceinline__ float bf2f(short b) {
    union { float f; unsigned u; } v; v.u = ((unsigned)(unsigned short)b) << 16;
    return v.f;
}

// Kernel 1: h = x@W (fp32); emit hT (bf16, [D][N]), e_src, e_dst.
// v2: W staged through double-buffered LDS chunks (16 rows) with register
// prefetch -> inner loop is pure LDS+FMA (no global-load latency chains).
// Column map: thread owns cols {m*32 + (t&7)*4 + j} so W_s reads are
// consecutive 128B per (k,m) -> 8-way broadcast, conflict-free.
__global__ __launch_bounds__(256) void gat_prep(
    const float* __restrict__ x, const float* __restrict__ W,
    const float* __restrict__ a,
    short* __restrict__ hT, float* __restrict__ e_src, float* __restrict__ e_dst)
{
    __shared__ float x_s[32][260];          // +4 pad: il*260%32 = il*4 -> distinct banks
    __shared__ float W_s[2][16][256];       // 16-row W chunk, double-buffered
    const int t  = threadIdx.x;
    const int ib = blockIdx.x * 32;

    // stage x tile [32][256] coalesced
    #pragma unroll
    for (int rep = 0; rep < 8; ++rep) {
        int fi = rep * 256 + t;
        int r  = fi >> 6;
        int c4 = (fi & 63) * 4;
        float4 v = *(const float4*)(x + (size_t)(ib + r) * DD + c4);
        *(float4*)&x_s[r][c4] = v;
    }
    // prefetch W chunk 0 into registers (4 float4/thread = one 16x256 chunk/block)
    float4 wp[4];
    #pragma unroll
    for (int q = 0; q < 4; ++q) {
        int fi = q * 256 + t;
        wp[q] = *(const float4*)(W + (size_t)(fi >> 6) * DD + (fi & 63) * 4);
    }
    __syncthreads();

    const int il = t >> 3;                  // local row 0..31
    const int dg = (t & 7) * 4;             // col offset within each 32-col group
    f32x4 acc[8];
    #pragma unroll
    for (int m = 0; m < 8; ++m) acc[m] = (f32x4){0.f, 0.f, 0.f, 0.f};

    for (int kc = 0; kc < 16; ++kc) {
        const int b = kc & 1;
        #pragma unroll
        for (int q = 0; q < 4; ++q) {       // write prefetched chunk -> LDS
            int fi = q * 256 + t;
            *(float4*)&W_s[b][fi >> 6][(fi & 63) * 4] = wp[q];
        }
        if (kc < 15) {                      // prefetch next chunk (consumed next iter)
            #pragma unroll
            for (int q = 0; q < 4; ++q) {
                int fi = q * 256 + t;
                wp[q] = *(const float4*)(W + (size_t)((kc + 1) * 16 + (fi >> 6)) * DD + (fi & 63) * 4);
            }
        }
        __syncthreads();                    // one barrier/chunk (dbuf covers reuse)
        #pragma unroll
        for (int kl = 0; kl < 16; ++kl) {
            float xv = x_s[il][kc * 16 + kl];
            #pragma unroll
            for (int m = 0; m < 8; ++m) {
                float4 wv = *(const float4*)&W_s[b][kl][m * 32 + dg];
                acc[m].x += xv * wv.x; acc[m].y += xv * wv.y;
                acc[m].z += xv * wv.z; acc[m].w += xv * wv.w;
            }
        }
    }

    const int ig = ib + il;
    float p1 = 0.f, p2 = 0.f;
    #pragma unroll
    for (int m = 0; m < 8; ++m) {
        #pragma unroll
        for (int j = 0; j < 4; ++j) {
            int col = m * 32 + dg + j;
            float hv = acc[m][j];
            p1 += hv * a[col];
            p2 += hv * a[DD + col];
            hT[(size_t)col * NN + ig] = f2bf(hv);
        }
    }
    p1 += __shfl_xor(p1, 1); p1 += __shfl_xor(p1, 2); p1 += __shfl_xor(p1, 4);
    p2 += __shfl_xor(p2, 1); p2 += __shfl_xor(p2, 2); p2 += __shfl_xor(p2, 4);
    if ((t & 7) == 0) { e_src[ig] = p1; e_dst[ig] = p2; }
}

// Kernel 2: fused masked softmax + attention@h. v2: prefetch TWO K-steps
// ahead (sets A/B, 2x unrolled) so ~900cy HBM latency is covered by ~2
// step-times. Structure otherwise identical to the verified v1.
__global__ __launch_bounds__(512) void gat_main(
    const int* __restrict__ adj, const short* __restrict__ hT,
    const float* __restrict__ e_src, const float* __restrict__ e_dst,
    float* __restrict__ out)
{
    __shared__ __align__(16) short B_s[2][256][40];   // hT panel, stride 40 (2-way = free)
    __shared__ __align__(16) short w_s[2][32][40];    // weight tile bf16
    __shared__ float denom_s[32];

    const int t    = threadIdx.x;
    const int lane = t & 63;
    const int wid  = t >> 6;
    const int ibl  = blockIdx.x * 32;

    const int irow = t >> 4;                  // 0..31
    const int jc2  = (t & 15) * 2;
    const float es = e_src[ibl + irow];
    const int* adj_row = adj + (size_t)(ibl + irow) * NN;
    const short* hrow = hT + (size_t)(t >> 1) * NN + (t & 1) * 16;

    const int ihalf = wid & 1;
    const int dbase = (wid >> 1) * 64;
    const int arow  = lane & 15;              // frag row (A) / col (B,D)
    const int kg8   = (lane >> 4) * 8;        // frag k-chunk

    float dsum = 0.f;
    f32x4 acc0 = {0.f,0.f,0.f,0.f}, acc1 = acc0, acc2 = acc0, acc3 = acc0;

    // 2-deep prefetch: set A = even steps, set B = odd steps
    int2   adA = *(const int2*)(adj_row + jc2);
    float2 edA = *(const float2*)(e_dst + jc2);
    int4   h0A = *(const int4*)(hrow);
    int4   h1A = *(const int4*)(hrow + 8);
    int2   adB = *(const int2*)(adj_row + 32 + jc2);
    float2 edB = *(const float2*)(e_dst + 32 + jc2);
    int4   h0B = *(const int4*)(hrow + 32);
    int4   h1B = *(const int4*)(hrow + 32 + 8);

#define MAIN_STEP(AD, ED, H0, H1, n)                                           \
    {                                                                          \
        const int c = (n) & 1;                                                 \
        float s0 = es + ED.x, s1 = es + ED.y;                                  \
        float l0 = s0 > 0.f ? s0 : 0.01f * s0;                                 \
        float l1 = s1 > 0.f ? s1 : 0.01f * s1;                                 \
        float w0 = AD.x > 0 ? __expf(l0) : 0.f;                                \
        float w1 = AD.y > 0 ? __expf(l1) : 0.f;                                \
        short b0 = f2bf(w0), b1 = f2bf(w1);                                    \
        dsum += bf2f(b0) + bf2f(b1);    /* denom = SAME bf16-rounded weights */\
        *(unsigned*)&w_s[c][irow][jc2] =                                       \
            (unsigned)(unsigned short)b0 | ((unsigned)(unsigned short)b1 << 16);\
        *(int4*)&B_s[c][t >> 1][(t & 1) * 16]     = H0;                        \
        *(int4*)&B_s[c][t >> 1][(t & 1) * 16 + 8] = H1;                        \
        int jn = (((n) + 2) & (NN / 32 - 1)) * 32;  /* prefetch 2 ahead */     \
        AD = *(const int2*)(adj_row + jn + jc2);                               \
        ED = *(const float2*)(e_dst + jn + jc2);                               \
        H0 = *(const int4*)(hrow + jn);                                        \
        H1 = *(const int4*)(hrow + jn + 8);                                    \
        __syncthreads();                 /* single barrier/step (dbuf LDS) */  \
        short8 af  = *(const short8*)&w_s[c][ihalf * 16 + arow][kg8];          \
        short8 bf0 = *(const short8*)&B_s[c][dbase +  0 + arow][kg8];          \
        short8 bf1 = *(const short8*)&B_s[c][dbase + 16 + arow][kg8];          \
        short8 bf2 = *(const short8*)&B_s[c][dbase + 32 + arow][kg8];          \
        short8 bf3 = *(const short8*)&B_s[c][dbase + 48 + arow][kg8];          \
        acc0 = __builtin_amdgcn_mfma_f32_16x16x32_bf16(af, bf0, acc0, 0, 0, 0);\
        acc1 = __builtin_amdgcn_mfma_f32_16x16x32_bf16(af, bf1, acc1, 0, 0, 0);\
        acc2 = __builtin_amdgcn_mfma_f32_16x16x32_bf16(af, bf2, acc2, 0, 0, 0);\
        acc3 = __builtin_amdgcn_mfma_f32_16x16x32_bf16(af, bf3, acc3, 0, 0, 0);\
    }

    for (int n = 0; n < NN / 32; n += 2) {
        MAIN_STEP(adA, edA, h0A, h1A, n)
        MAIN_STEP(adB, edB, h0B, h1B, n + 1)
    }
#undef MAIN_STEP

    // denom: 16 threads per row -> shfl tree
    dsum += __shfl_xor(dsum, 1);
    dsum += __shfl_xor(dsum, 2);
    dsum += __shfl_xor(dsum, 4);
    dsum += __shfl_xor(dsum, 8);
    if ((t & 15) == 0) denom_s[irow] = dsum;
    __syncthreads();

    // epilogue: D-frag row=(lane>>4)*4+r, col=lane&15
    const int rbase = ihalf * 16 + (lane >> 4) * 4;
    #pragma unroll
    for (int r = 0; r < 4; ++r) {
        float inv = 1.f / denom_s[rbase + r];
        size_t o = (size_t)(ibl + rbase + r) * DD + dbase + arow;
        float v0 = acc0[r] * inv; v0 = v0 > 0.f ? v0 : expm1f(v0);
        float v1 = acc1[r] * inv; v1 = v1 > 0.f ? v1 : expm1f(v1);
        float v2 = acc2[r] * inv; v2 = v2 > 0.f ? v2 : expm1f(v2);
        float v3 = acc3[r] * inv; v3 = v3 > 0.f ? v3 : expm1f(v3);
        out[o] = v0; out[o + 16] = v1; out[o + 32] = v2; out[o + 48] = v3;
    }
}

extern "C" void kernel_launch(void* const* d_in, const int* in_sizes, int n_in,
                              void* d_out, int out_size, void* d_ws, size_t ws_size,
                              hipStream_t stream) {
    const float* x   = (const float*)d_in[0];
    const int*   adj = (const int*)d_in[1];
    const float* W   = (const float*)d_in[2];
    const float* a   = (const float*)d_in[3];
    float* out = (float*)d_out;

    // workspace: hT bf16 [256][8192] (4 MB) | e_src [8192] f32 | e_dst [8192] f32
    short* hT   = (short*)d_ws;
    float* esrc = (float*)((char*)d_ws + (size_t)DD * NN * 2);
    float* edst = esrc + NN;

    gat_prep<<<dim3(NN / 32), dim3(256), 0, stream>>>(x, W, a, hT, esrc, edst);
    gat_main<<<dim3(NN / 32), dim3(512), 0, stream>>>(adj, hT, esrc, edst, out);
}